// Round 1
// baseline (560.545 us; speedup 1.0000x reference)
//
#include <hip/hip_runtime.h>
#include <math.h>

#define N_   64
#define L_   1024
#define H_   1024
#define NCH  8

// ws float offsets
#define T_OFF    0          // t[n][h]            65536  (memset 0)
#define ACC_OFF  65536      // acc[n][h]          65536  (memset 0)
#define PRAW_OFF 131072     // praw^T[g][n]       65536  (memset 0)
#define PMZ_OFF  196608     // (m,Z)[n][ch]       1024
#define PC_OFF   197632     // pc[n][ch][h]       524288
#define CAT_OFF  721920     // cat[n][2H]         131072
// total 852992 floats = 3.25 MB

// ---------------- K1: t = output@W_a (split-g) ; praw^T = output@W_p^T (split-h) ----
__global__ __launch_bounds__(256) void k1_prep(const float* __restrict__ outp,
                                               const float* __restrict__ Wa,
                                               const float* __restrict__ Wp,
                                               float* __restrict__ ws) {
    float* t    = ws + T_OFF;
    float* praw = ws + PRAW_OFF;
    const int tid = threadIdx.x;
    const int bid = blockIdx.x;

    float acc[N_];
#pragma unroll
    for (int n = 0; n < N_; ++n) acc[n] = 0.f;

    if (bid < 64) {
        // t[n,h] = sum_g outp[n,g] * Wa[g,h]   (reduce over Wa row index)
        const int ht = bid & 3, gc = bid >> 2;     // 4 h-tiles x 16 g-chunks(64)
        const int h  = ht * 256 + tid;
        const int g0c = gc * 64;
        for (int gq = 0; gq < 16; ++gq) {
            const int g0 = g0c + gq * 4;
            const float w0 = Wa[(size_t)(g0 + 0) * H_ + h];
            const float w1 = Wa[(size_t)(g0 + 1) * H_ + h];
            const float w2 = Wa[(size_t)(g0 + 2) * H_ + h];
            const float w3 = Wa[(size_t)(g0 + 3) * H_ + h];
#pragma unroll
            for (int n = 0; n < N_; ++n) {
                const float4 ov = *(const float4*)(outp + (size_t)n * H_ + g0);
                acc[n] = fmaf(ov.x, w0, fmaf(ov.y, w1, fmaf(ov.z, w2, fmaf(ov.w, w3, acc[n]))));
            }
        }
#pragma unroll
        for (int n = 0; n < N_; ++n) atomicAdd(&t[(size_t)n * H_ + h], acc[n]);
    } else {
        // praw[g,n] = sum_h outp[n,h] * Wp[g,h]  (reduce over Wp col index), stored transposed
        const int b = bid - 64;
        const int gt = b & 3, hc = b >> 2;         // 4 g-tiles x 16 h-chunks(64)
        const int g  = gt * 256 + tid;
        const int h0c = hc * 64;
        for (int hq = 0; hq < 16; ++hq) {
            const int h0 = h0c + hq * 4;
            const float4 wv = *(const float4*)(Wp + (size_t)g * H_ + h0);
#pragma unroll
            for (int n = 0; n < N_; ++n) {
                const float4 ov = *(const float4*)(outp + (size_t)n * H_ + h0);
                acc[n] = fmaf(ov.x, wv.x, fmaf(ov.y, wv.y, fmaf(ov.z, wv.z, fmaf(ov.w, wv.w, acc[n]))));
            }
        }
#pragma unroll
        for (int n = 0; n < N_; ++n) atomicAdd(&praw[(size_t)g * N_ + n], acc[n]);
    }
}

// ---------------- K2: stream enc, online softmax * gauss, partial contexts --------
__global__ __launch_bounds__(256) void k2_stream(const float* __restrict__ enc,
                                                 const float* __restrict__ vp,
                                                 float* __restrict__ ws) {
    __shared__ float red[256];
    __shared__ float Cb[4 * 1024];
    __shared__ float mzs[8];
    __shared__ float pt_s;

    const float* t    = ws + T_OFF;
    const float* praw = ws + PRAW_OFF;
    float* pmz = ws + PMZ_OFF;
    float* pc  = ws + PC_OFF;

    const int tid = threadIdx.x;
    const int bid = blockIdx.x;
    const int n   = bid >> 3;
    const int ch  = bid & 7;
    const int wid = tid >> 6;
    const int j   = tid & 63;

    // prologue: p_t = H * sigmoid( sum_g tanh(praw[g,n]) * vp[g] )
    float partial = 0.f;
#pragma unroll
    for (int k = 0; k < 4; ++k) {
        const int g = tid + k * 256;
        partial += tanhf(praw[(size_t)g * N_ + n]) * vp[g];
    }
    red[tid] = partial;
    __syncthreads();
    for (int s = 128; s > 0; s >>= 1) {
        if (tid < s) red[tid] += red[tid + s];
        __syncthreads();
    }
    if (tid == 0) pt_s = (float)H_ / (1.f + __expf(-red[0]));
    __syncthreads();
    const float p_t = pt_s;

    // per-lane t fragment (h = k*256 + j*4 + e)
    const float* tb = t + (size_t)n * H_ + j * 4;
    const float4 t0 = *(const float4*)(tb);
    const float4 t1 = *(const float4*)(tb + 256);
    const float4 t2 = *(const float4*)(tb + 512);
    const float4 t3 = *(const float4*)(tb + 768);

    float m = -INFINITY, Z = 0.f;
    float4 C0 = make_float4(0, 0, 0, 0), C1 = C0, C2 = C0, C3 = C0;

    const int l0 = ch * 128 + wid * 32;
    const float* rp = enc + ((size_t)n * L_ + l0) * H_ + j * 4;

    float4 e0 = *(const float4*)(rp);
    float4 e1 = *(const float4*)(rp + 256);
    float4 e2 = *(const float4*)(rp + 512);
    float4 e3 = *(const float4*)(rp + 768);

    for (int i = 0; i < 32; ++i) {
        float4 f0, f1, f2, f3;
        if (i < 31) {  // prefetch next row
            const float* nx = rp + (size_t)(i + 1) * H_;
            f0 = *(const float4*)(nx);
            f1 = *(const float4*)(nx + 256);
            f2 = *(const float4*)(nx + 512);
            f3 = *(const float4*)(nx + 768);
        }
        float pd = e0.x * t0.x;
        pd = fmaf(e0.y, t0.y, pd); pd = fmaf(e0.z, t0.z, pd); pd = fmaf(e0.w, t0.w, pd);
        pd = fmaf(e1.x, t1.x, pd); pd = fmaf(e1.y, t1.y, pd); pd = fmaf(e1.z, t1.z, pd); pd = fmaf(e1.w, t1.w, pd);
        pd = fmaf(e2.x, t2.x, pd); pd = fmaf(e2.y, t2.y, pd); pd = fmaf(e2.z, t2.z, pd); pd = fmaf(e2.w, t2.w, pd);
        pd = fmaf(e3.x, t3.x, pd); pd = fmaf(e3.y, t3.y, pd); pd = fmaf(e3.z, t3.z, pd); pd = fmaf(e3.w, t3.w, pd);
        pd += __shfl_xor(pd, 1, 64);
        pd += __shfl_xor(pd, 2, 64);
        pd += __shfl_xor(pd, 4, 64);
        pd += __shfl_xor(pd, 8, 64);
        pd += __shfl_xor(pd, 16, 64);
        pd += __shfl_xor(pd, 32, 64);

        const int l = l0 + i;
        const float d = (float)l - p_t;
        const float gw = __expf(d * d * (-1.f / 25.f));

        if (pd > m) {  // wave-uniform branch
            const float r = __expf(m - pd);
            Z *= r;
            C0.x *= r; C0.y *= r; C0.z *= r; C0.w *= r;
            C1.x *= r; C1.y *= r; C1.z *= r; C1.w *= r;
            C2.x *= r; C2.y *= r; C2.z *= r; C2.w *= r;
            C3.x *= r; C3.y *= r; C3.z *= r; C3.w *= r;
            m = pd;
        }
        const float e = __expf(pd - m);
        Z += e;
        const float w = e * gw;
        C0.x = fmaf(w, e0.x, C0.x); C0.y = fmaf(w, e0.y, C0.y); C0.z = fmaf(w, e0.z, C0.z); C0.w = fmaf(w, e0.w, C0.w);
        C1.x = fmaf(w, e1.x, C1.x); C1.y = fmaf(w, e1.y, C1.y); C1.z = fmaf(w, e1.z, C1.z); C1.w = fmaf(w, e1.w, C1.w);
        C2.x = fmaf(w, e2.x, C2.x); C2.y = fmaf(w, e2.y, C2.y); C2.z = fmaf(w, e2.z, C2.z); C2.w = fmaf(w, e2.w, C2.w);
        C3.x = fmaf(w, e3.x, C3.x); C3.y = fmaf(w, e3.y, C3.y); C3.z = fmaf(w, e3.z, C3.z); C3.w = fmaf(w, e3.w, C3.w);
        e0 = f0; e1 = f1; e2 = f2; e3 = f3;
    }

    // block combine (4 waves)
    if (j == 0) { mzs[wid * 2] = m; mzs[wid * 2 + 1] = Z; }
    __syncthreads();
    const float mb = fmaxf(fmaxf(mzs[0], mzs[2]), fmaxf(mzs[4], mzs[6]));
    const float sc = __expf(m - mb);
    float* cw = Cb + wid * 1024 + j * 4;
    *(float4*)(cw)       = make_float4(C0.x * sc, C0.y * sc, C0.z * sc, C0.w * sc);
    *(float4*)(cw + 256) = make_float4(C1.x * sc, C1.y * sc, C1.z * sc, C1.w * sc);
    *(float4*)(cw + 512) = make_float4(C2.x * sc, C2.y * sc, C2.z * sc, C2.w * sc);
    *(float4*)(cw + 768) = make_float4(C3.x * sc, C3.y * sc, C3.z * sc, C3.w * sc);
    __syncthreads();
#pragma unroll
    for (int k = 0; k < 4; ++k) {
        const int h = k * 256 + tid;
        const float s = Cb[h] + Cb[1024 + h] + Cb[2048 + h] + Cb[3072 + h];
        pc[((size_t)n * NCH + ch) * H_ + h] = s;
    }
    if (tid == 0) {
        float zb = 0.f;
#pragma unroll
        for (int w2 = 0; w2 < 4; ++w2) zb += mzs[w2 * 2 + 1] * __expf(mzs[w2 * 2] - mb);
        pmz[((size_t)n * NCH + ch) * 2]     = mb;
        pmz[((size_t)n * NCH + ch) * 2 + 1] = zb;
    }
}

// ---------------- K3: combine chunk partials -> cat = [context, output] ----------
__global__ __launch_bounds__(256) void k3_combine(const float* __restrict__ outp,
                                                  float* __restrict__ ws) {
    const float* pmz = ws + PMZ_OFF;
    const float* pc  = ws + PC_OFF;
    float* cat = ws + CAT_OFF;
    const int n = blockIdx.x, tid = threadIdx.x;

    float mv[NCH], zv[NCH], wv[NCH];
    float mt = -INFINITY;
#pragma unroll
    for (int c = 0; c < NCH; ++c) {
        mv[c] = pmz[((size_t)n * NCH + c) * 2];
        zv[c] = pmz[((size_t)n * NCH + c) * 2 + 1];
        mt = fmaxf(mt, mv[c]);
    }
    float zt = 0.f;
#pragma unroll
    for (int c = 0; c < NCH; ++c) { wv[c] = __expf(mv[c] - mt); zt += zv[c] * wv[c]; }
    const float inv = 1.f / zt;
#pragma unroll
    for (int k = 0; k < 4; ++k) {
        const int h = k * 256 + tid;
        float s = 0.f;
#pragma unroll
        for (int c = 0; c < NCH; ++c) s += pc[((size_t)n * NCH + c) * H_ + h] * wv[c];
        cat[(size_t)n * 2048 + h]        = s * inv;
        cat[(size_t)n * 2048 + 1024 + h] = outp[(size_t)n * H_ + h];
    }
}

// ---------------- K4: acc[n,h] += cat[n,:] . Wc[h,:]  (wave = 4h x c-quarter) ----
__global__ __launch_bounds__(256) void k4_gemm(const float* __restrict__ Wc,
                                               float* __restrict__ ws) {
    const float* cat = ws + CAT_OFF;
    float* acc = ws + ACC_OFF;
    const int tid = threadIdx.x;
    const int wid = tid >> 6, j = tid & 63;
    const int wg = blockIdx.x * 4 + wid;  // 0..1023
    const int hg = wg >> 2;               // h-group 0..255
    const int q  = wg & 3;                // c-quarter
    const int cs = q * 512 + j * 8;
    const int h0 = hg * 4;

    float4 wA[4], wB[4];
#pragma unroll
    for (int r = 0; r < 4; ++r) {
        const float* wr = Wc + (size_t)(h0 + r) * 2048 + cs;
        wA[r] = *(const float4*)(wr);
        wB[r] = *(const float4*)(wr + 4);
    }
    for (int n = 0; n < N_; ++n) {
        const float* cr = cat + (size_t)n * 2048 + cs;
        const float4 xA = *(const float4*)(cr);
        const float4 xB = *(const float4*)(cr + 4);
        float d0, d1, d2, d3;
        d0 = xA.x * wA[0].x; d0 = fmaf(xA.y, wA[0].y, d0); d0 = fmaf(xA.z, wA[0].z, d0); d0 = fmaf(xA.w, wA[0].w, d0);
        d0 = fmaf(xB.x, wB[0].x, d0); d0 = fmaf(xB.y, wB[0].y, d0); d0 = fmaf(xB.z, wB[0].z, d0); d0 = fmaf(xB.w, wB[0].w, d0);
        d1 = xA.x * wA[1].x; d1 = fmaf(xA.y, wA[1].y, d1); d1 = fmaf(xA.z, wA[1].z, d1); d1 = fmaf(xA.w, wA[1].w, d1);
        d1 = fmaf(xB.x, wB[1].x, d1); d1 = fmaf(xB.y, wB[1].y, d1); d1 = fmaf(xB.z, wB[1].z, d1); d1 = fmaf(xB.w, wB[1].w, d1);
        d2 = xA.x * wA[2].x; d2 = fmaf(xA.y, wA[2].y, d2); d2 = fmaf(xA.z, wA[2].z, d2); d2 = fmaf(xA.w, wA[2].w, d2);
        d2 = fmaf(xB.x, wB[2].x, d2); d2 = fmaf(xB.y, wB[2].y, d2); d2 = fmaf(xB.z, wB[2].z, d2); d2 = fmaf(xB.w, wB[2].w, d2);
        d3 = xA.x * wA[3].x; d3 = fmaf(xA.y, wA[3].y, d3); d3 = fmaf(xA.z, wA[3].z, d3); d3 = fmaf(xA.w, wA[3].w, d3);
        d3 = fmaf(xB.x, wB[3].x, d3); d3 = fmaf(xB.y, wB[3].y, d3); d3 = fmaf(xB.z, wB[3].z, d3); d3 = fmaf(xB.w, wB[3].w, d3);
#pragma unroll
        for (int msk = 1; msk < 64; msk <<= 1) {
            d0 += __shfl_xor(d0, msk, 64);
            d1 += __shfl_xor(d1, msk, 64);
            d2 += __shfl_xor(d2, msk, 64);
            d3 += __shfl_xor(d3, msk, 64);
        }
        if (j == 0) atomicAdd(&acc[(size_t)n * H_ + h0 + 0], d0);
        if (j == 1) atomicAdd(&acc[(size_t)n * H_ + h0 + 1], d1);
        if (j == 2) atomicAdd(&acc[(size_t)n * H_ + h0 + 2], d2);
        if (j == 3) atomicAdd(&acc[(size_t)n * H_ + h0 + 3], d3);
    }
}

// ---------------- K5: out = tanh(acc) --------------------------------------------
__global__ __launch_bounds__(256) void k5_tanh(const float* __restrict__ accp,
                                               float* __restrict__ out) {
    const int i = (blockIdx.x * 256 + threadIdx.x) * 4;
    const float4 v = *(const float4*)(accp + i);
    float4 r;
    r.x = tanhf(v.x); r.y = tanhf(v.y); r.z = tanhf(v.z); r.w = tanhf(v.w);
    *(float4*)(out + i) = r;
}

extern "C" void kernel_launch(void* const* d_in, const int* in_sizes, int n_in,
                              void* d_out, int out_size, void* d_ws, size_t ws_size,
                              hipStream_t stream) {
    const float* enc  = (const float*)d_in[0];
    const float* outp = (const float*)d_in[1];
    // d_in[2] = time_step (unused by the reference math)
    const float* Wa   = (const float*)d_in[3];
    const float* Wp   = (const float*)d_in[4];
    const float* vp   = (const float*)d_in[5];
    const float* Wc   = (const float*)d_in[6];
    float* ws  = (float*)d_ws;
    float* out = (float*)d_out;

    // zero t, acc, praw (atomic accumulation targets)
    hipMemsetAsync(d_ws, 0, (size_t)(3 * 65536) * sizeof(float), stream);

    hipLaunchKernelGGL(k1_prep,    dim3(128), dim3(256), 0, stream, outp, Wa, Wp, ws);
    hipLaunchKernelGGL(k2_stream,  dim3(512), dim3(256), 0, stream, enc, vp, ws);
    hipLaunchKernelGGL(k3_combine, dim3(64),  dim3(256), 0, stream, outp, ws);
    hipLaunchKernelGGL(k4_gemm,    dim3(256), dim3(256), 0, stream, Wc, ws);
    hipLaunchKernelGGL(k5_tanh,    dim3(64),  dim3(256), 0, stream, ws + ACC_OFF, out);
}

// Round 2
// 495.694 us; speedup vs baseline: 1.1308x; 1.1308x over previous
//
#include <hip/hip_runtime.h>
#include <math.h>

#define N_   64
#define L_   1024
#define H_   1024
#define NCH  16

// ws float offsets (no memset needed anywhere — every slot written before read)
#define T_OFF     0          // t[n][h]                    65536
#define PT_OFF    65536      // p_t[n]                     64 (pad 256)
#define TP_OFF    65792      // t partials [gc=16][n][h]   1048576
#define PRAWP_OFF 1114368    // praw partials [hc=16][n][g] 1048576
#define PMZ_OFF   2162944    // (m,Z)[n][ch=16]            2048
#define PC_OFF    2164992    // pc[n][ch][h]               1048576
#define CAT_OFF   3213568    // cat[n][2H]                 131072
#define PACC_OFF  3344640    // pacc[q=4][n][h]            262144
// total ~3.6M floats = 14.4 MB

// ---- K1: t-partials = output@W_a (split-g, no atomics); praw-partials = output@W_p^T (split-h) ----
__global__ __launch_bounds__(256) void k1_prep(const float* __restrict__ outp,
                                               const float* __restrict__ Wa,
                                               const float* __restrict__ Wp,
                                               float* __restrict__ ws) {
    float* tp    = ws + TP_OFF;
    float* prawp = ws + PRAWP_OFF;
    const int tid = threadIdx.x;
    const int bid = blockIdx.x;

    float acc[N_];
#pragma unroll
    for (int n = 0; n < N_; ++n) acc[n] = 0.f;

    if (bid < 64) {
        // t_p[gc][n][h] = sum_{g in chunk} outp[n,g] * Wa[g,h]
        const int ht = bid & 3, gc = bid >> 2;     // 4 h-tiles x 16 g-chunks(64)
        const int h  = ht * 256 + tid;
        const int g0c = gc * 64;
        for (int gq = 0; gq < 16; ++gq) {
            const int g0 = g0c + gq * 4;
            const float w0 = Wa[(size_t)(g0 + 0) * H_ + h];
            const float w1 = Wa[(size_t)(g0 + 1) * H_ + h];
            const float w2 = Wa[(size_t)(g0 + 2) * H_ + h];
            const float w3 = Wa[(size_t)(g0 + 3) * H_ + h];
#pragma unroll
            for (int n = 0; n < N_; ++n) {
                const float4 ov = *(const float4*)(outp + (size_t)n * H_ + g0);
                acc[n] = fmaf(ov.x, w0, fmaf(ov.y, w1, fmaf(ov.z, w2, fmaf(ov.w, w3, acc[n]))));
            }
        }
#pragma unroll
        for (int n = 0; n < N_; ++n) tp[((size_t)(gc * 64 + n)) * H_ + h] = acc[n];
    } else {
        // praw_p[hc][n][g] = sum_{h in chunk} outp[n,h] * Wp[g,h]
        const int b = bid - 64;
        const int gt = b & 3, hc = b >> 2;         // 4 g-tiles x 16 h-chunks(64)
        const int g  = gt * 256 + tid;
        const int h0c = hc * 64;
        for (int hq = 0; hq < 16; ++hq) {
            const int h0 = h0c + hq * 4;
            const float4 wv = *(const float4*)(Wp + (size_t)g * H_ + h0);
#pragma unroll
            for (int n = 0; n < N_; ++n) {
                const float4 ov = *(const float4*)(outp + (size_t)n * H_ + h0);
                acc[n] = fmaf(ov.x, wv.x, fmaf(ov.y, wv.y, fmaf(ov.z, wv.z, fmaf(ov.w, wv.w, acc[n]))));
            }
        }
#pragma unroll
        for (int n = 0; n < N_; ++n) prawp[((size_t)(hc * 64 + n)) * H_ + g] = acc[n];
    }
}

// ---- K1b: finalize t[n][h] (sum 16 g-chunks) and p_t[n] (tanh·vp reduce) --------
__global__ __launch_bounds__(256) void k1b_final(const float* __restrict__ vp,
                                                 float* __restrict__ ws) {
    const float* tp    = ws + TP_OFF;
    const float* prawp = ws + PRAWP_OFF;
    float* t  = ws + T_OFF;
    float* pt = ws + PT_OFF;
    const int tid = threadIdx.x;
    const int bid = blockIdx.x;

    if (bid < 64) {
        const int n = bid;
        const int h0 = tid * 4;
        float4 s = make_float4(0, 0, 0, 0);
#pragma unroll
        for (int gc = 0; gc < 16; ++gc) {
            const float4 v = *(const float4*)(tp + ((size_t)(gc * 64 + n)) * H_ + h0);
            s.x += v.x; s.y += v.y; s.z += v.z; s.w += v.w;
        }
        *(float4*)(t + (size_t)n * H_ + h0) = s;
    } else {
        __shared__ float red[256];
        const int n = bid - 64;
        const int g0 = tid * 4;
        float4 s = make_float4(0, 0, 0, 0);
#pragma unroll
        for (int hc = 0; hc < 16; ++hc) {
            const float4 v = *(const float4*)(prawp + ((size_t)(hc * 64 + n)) * H_ + g0);
            s.x += v.x; s.y += v.y; s.z += v.z; s.w += v.w;
        }
        const float4 vv = *(const float4*)(vp + g0);
        float part = tanhf(s.x) * vv.x + tanhf(s.y) * vv.y + tanhf(s.z) * vv.z + tanhf(s.w) * vv.w;
        red[tid] = part;
        __syncthreads();
        for (int st = 128; st > 0; st >>= 1) {
            if (tid < st) red[tid] += red[tid + st];
            __syncthreads();
        }
        if (tid == 0) pt[n] = (float)H_ / (1.f + __expf(-red[0]));
    }
}

// ---- K2: stream enc once, online softmax * gauss, partial contexts --------------
__global__ __launch_bounds__(256, 4) void k2_stream(const float* __restrict__ enc,
                                                    float* __restrict__ ws) {
    __shared__ float Cb[4 * 1024];
    __shared__ float mzs[8];

    const float* t  = ws + T_OFF;
    const float* pt = ws + PT_OFF;
    float* pmz = ws + PMZ_OFF;
    float* pc  = ws + PC_OFF;

    const int tid = threadIdx.x;
    const int bid = blockIdx.x;
    const int n   = bid >> 4;
    const int ch  = bid & 15;
    const int wid = tid >> 6;
    const int j   = tid & 63;

    const float p_t = pt[n];

    // per-lane t fragment (h = k*256 + j*4 + e)
    const float* tb = t + (size_t)n * H_ + j * 4;
    const float4 t0 = *(const float4*)(tb);
    const float4 t1 = *(const float4*)(tb + 256);
    const float4 t2 = *(const float4*)(tb + 512);
    const float4 t3 = *(const float4*)(tb + 768);

    float m = -INFINITY, Z = 0.f;
    float4 C0 = make_float4(0, 0, 0, 0), C1 = C0, C2 = C0, C3 = C0;

    const int l0 = ch * 64 + wid * 16;
    const float* rp = enc + ((size_t)n * L_ + l0) * H_ + j * 4;

    float4 e0 = *(const float4*)(rp);
    float4 e1 = *(const float4*)(rp + 256);
    float4 e2 = *(const float4*)(rp + 512);
    float4 e3 = *(const float4*)(rp + 768);

    for (int i = 0; i < 16; ++i) {
        float4 f0, f1, f2, f3;
        if (i < 15) {  // prefetch next row
            const float* nx = rp + (size_t)(i + 1) * H_;
            f0 = *(const float4*)(nx);
            f1 = *(const float4*)(nx + 256);
            f2 = *(const float4*)(nx + 512);
            f3 = *(const float4*)(nx + 768);
        }
        float pd = e0.x * t0.x;
        pd = fmaf(e0.y, t0.y, pd); pd = fmaf(e0.z, t0.z, pd); pd = fmaf(e0.w, t0.w, pd);
        pd = fmaf(e1.x, t1.x, pd); pd = fmaf(e1.y, t1.y, pd); pd = fmaf(e1.z, t1.z, pd); pd = fmaf(e1.w, t1.w, pd);
        pd = fmaf(e2.x, t2.x, pd); pd = fmaf(e2.y, t2.y, pd); pd = fmaf(e2.z, t2.z, pd); pd = fmaf(e2.w, t2.w, pd);
        pd = fmaf(e3.x, t3.x, pd); pd = fmaf(e3.y, t3.y, pd); pd = fmaf(e3.z, t3.z, pd); pd = fmaf(e3.w, t3.w, pd);
        pd += __shfl_xor(pd, 1, 64);
        pd += __shfl_xor(pd, 2, 64);
        pd += __shfl_xor(pd, 4, 64);
        pd += __shfl_xor(pd, 8, 64);
        pd += __shfl_xor(pd, 16, 64);
        pd += __shfl_xor(pd, 32, 64);

        const int l = l0 + i;
        const float d = (float)l - p_t;
        const float gw = __expf(d * d * (-1.f / 25.f));

        if (pd > m) {  // wave-uniform branch
            const float r = __expf(m - pd);
            Z *= r;
            C0.x *= r; C0.y *= r; C0.z *= r; C0.w *= r;
            C1.x *= r; C1.y *= r; C1.z *= r; C1.w *= r;
            C2.x *= r; C2.y *= r; C2.z *= r; C2.w *= r;
            C3.x *= r; C3.y *= r; C3.z *= r; C3.w *= r;
            m = pd;
        }
        const float e = __expf(pd - m);
        Z += e;
        const float w = e * gw;
        C0.x = fmaf(w, e0.x, C0.x); C0.y = fmaf(w, e0.y, C0.y); C0.z = fmaf(w, e0.z, C0.z); C0.w = fmaf(w, e0.w, C0.w);
        C1.x = fmaf(w, e1.x, C1.x); C1.y = fmaf(w, e1.y, C1.y); C1.z = fmaf(w, e1.z, C1.z); C1.w = fmaf(w, e1.w, C1.w);
        C2.x = fmaf(w, e2.x, C2.x); C2.y = fmaf(w, e2.y, C2.y); C2.z = fmaf(w, e2.z, C2.z); C2.w = fmaf(w, e2.w, C2.w);
        C3.x = fmaf(w, e3.x, C3.x); C3.y = fmaf(w, e3.y, C3.y); C3.z = fmaf(w, e3.z, C3.z); C3.w = fmaf(w, e3.w, C3.w);
        e0 = f0; e1 = f1; e2 = f2; e3 = f3;
    }

    // block combine (4 waves)
    if (j == 0) { mzs[wid * 2] = m; mzs[wid * 2 + 1] = Z; }
    __syncthreads();
    const float mb = fmaxf(fmaxf(mzs[0], mzs[2]), fmaxf(mzs[4], mzs[6]));
    const float sc = __expf(m - mb);
    float* cw = Cb + wid * 1024 + j * 4;
    *(float4*)(cw)       = make_float4(C0.x * sc, C0.y * sc, C0.z * sc, C0.w * sc);
    *(float4*)(cw + 256) = make_float4(C1.x * sc, C1.y * sc, C1.z * sc, C1.w * sc);
    *(float4*)(cw + 512) = make_float4(C2.x * sc, C2.y * sc, C2.z * sc, C2.w * sc);
    *(float4*)(cw + 768) = make_float4(C3.x * sc, C3.y * sc, C3.z * sc, C3.w * sc);
    __syncthreads();
#pragma unroll
    for (int k = 0; k < 4; ++k) {
        const int h = k * 256 + tid;
        const float s = Cb[h] + Cb[1024 + h] + Cb[2048 + h] + Cb[3072 + h];
        pc[((size_t)n * NCH + ch) * H_ + h] = s;
    }
    if (tid == 0) {
        float zb = 0.f;
#pragma unroll
        for (int w2 = 0; w2 < 4; ++w2) zb += mzs[w2 * 2 + 1] * __expf(mzs[w2 * 2] - mb);
        pmz[((size_t)n * NCH + ch) * 2]     = mb;
        pmz[((size_t)n * NCH + ch) * 2 + 1] = zb;
    }
}

// ---- K3: combine chunk partials -> cat = [context, output] ----------------------
__global__ __launch_bounds__(256) void k3_combine(const float* __restrict__ outp,
                                                  float* __restrict__ ws) {
    const float* pmz = ws + PMZ_OFF;
    const float* pc  = ws + PC_OFF;
    float* cat = ws + CAT_OFF;
    const int n = blockIdx.x, tid = threadIdx.x;

    float mv[NCH], zv[NCH], wv[NCH];
    float mt = -INFINITY;
#pragma unroll
    for (int c = 0; c < NCH; ++c) {
        mv[c] = pmz[((size_t)n * NCH + c) * 2];
        zv[c] = pmz[((size_t)n * NCH + c) * 2 + 1];
        mt = fmaxf(mt, mv[c]);
    }
    float zt = 0.f;
#pragma unroll
    for (int c = 0; c < NCH; ++c) { wv[c] = __expf(mv[c] - mt); zt += zv[c] * wv[c]; }
    const float inv = 1.f / zt;
#pragma unroll
    for (int k = 0; k < 4; ++k) {
        const int h = k * 256 + tid;
        float s = 0.f;
#pragma unroll
        for (int c = 0; c < NCH; ++c) s += pc[((size_t)n * NCH + c) * H_ + h] * wv[c];
        cat[(size_t)n * 2048 + h]        = s * inv;
        cat[(size_t)n * 2048 + 1024 + h] = outp[(size_t)n * H_ + h];
    }
}

// ---- K4: pacc[q][n][h] = cat[n, quarter q] . Wc[h, quarter q]  (no atomics) -----
__global__ __launch_bounds__(256) void k4_gemm(const float* __restrict__ Wc,
                                               float* __restrict__ ws) {
    const float* cat = ws + CAT_OFF;
    float* pacc = ws + PACC_OFF;
    const int tid = threadIdx.x;
    const int wid = tid >> 6, j = tid & 63;
    const int wg = blockIdx.x * 4 + wid;  // 0..1023
    const int hg = wg >> 2;               // h-group 0..255
    const int q  = wg & 3;                // c-quarter
    const int cs = q * 512 + j * 8;
    const int h0 = hg * 4;

    float4 wA[4], wB[4];
#pragma unroll
    for (int r = 0; r < 4; ++r) {
        const float* wr = Wc + (size_t)(h0 + r) * 2048 + cs;
        wA[r] = *(const float4*)(wr);
        wB[r] = *(const float4*)(wr + 4);
    }
#pragma unroll 2
    for (int n = 0; n < N_; ++n) {
        const float* cr = cat + (size_t)n * 2048 + cs;
        const float4 xA = *(const float4*)(cr);
        const float4 xB = *(const float4*)(cr + 4);
        float d0, d1, d2, d3;
        d0 = xA.x * wA[0].x; d0 = fmaf(xA.y, wA[0].y, d0); d0 = fmaf(xA.z, wA[0].z, d0); d0 = fmaf(xA.w, wA[0].w, d0);
        d0 = fmaf(xB.x, wB[0].x, d0); d0 = fmaf(xB.y, wB[0].y, d0); d0 = fmaf(xB.z, wB[0].z, d0); d0 = fmaf(xB.w, wB[0].w, d0);
        d1 = xA.x * wA[1].x; d1 = fmaf(xA.y, wA[1].y, d1); d1 = fmaf(xA.z, wA[1].z, d1); d1 = fmaf(xA.w, wA[1].w, d1);
        d1 = fmaf(xB.x, wB[1].x, d1); d1 = fmaf(xB.y, wB[1].y, d1); d1 = fmaf(xB.z, wB[1].z, d1); d1 = fmaf(xB.w, wB[1].w, d1);
        d2 = xA.x * wA[2].x; d2 = fmaf(xA.y, wA[2].y, d2); d2 = fmaf(xA.z, wA[2].z, d2); d2 = fmaf(xA.w, wA[2].w, d2);
        d2 = fmaf(xB.x, wB[2].x, d2); d2 = fmaf(xB.y, wB[2].y, d2); d2 = fmaf(xB.z, wB[2].z, d2); d2 = fmaf(xB.w, wB[2].w, d2);
        d3 = xA.x * wA[3].x; d3 = fmaf(xA.y, wA[3].y, d3); d3 = fmaf(xA.z, wA[3].z, d3); d3 = fmaf(xA.w, wA[3].w, d3);
        d3 = fmaf(xB.x, wB[3].x, d3); d3 = fmaf(xB.y, wB[3].y, d3); d3 = fmaf(xB.z, wB[3].z, d3); d3 = fmaf(xB.w, wB[3].w, d3);
#pragma unroll
        for (int msk = 1; msk < 64; msk <<= 1) {
            d0 += __shfl_xor(d0, msk, 64);
            d1 += __shfl_xor(d1, msk, 64);
            d2 += __shfl_xor(d2, msk, 64);
            d3 += __shfl_xor(d3, msk, 64);
        }
        if (j == 0) {  // all lanes hold the reduced sums; lane 0 stores one float4
            *(float4*)(pacc + ((size_t)(q * N_ + n)) * H_ + h0) = make_float4(d0, d1, d2, d3);
        }
    }
}

// ---- K5: out = tanh(sum_q pacc[q]) ----------------------------------------------
__global__ __launch_bounds__(256) void k5_tanh(float* __restrict__ ws,
                                               float* __restrict__ out) {
    const float* pacc = ws + PACC_OFF;
    const int i = (blockIdx.x * 256 + threadIdx.x) * 4;  // i over 64*1024
    float4 s = *(const float4*)(pacc + i);
    const float4 a = *(const float4*)(pacc + 65536 + i);
    const float4 b = *(const float4*)(pacc + 131072 + i);
    const float4 c = *(const float4*)(pacc + 196608 + i);
    s.x += a.x + b.x + c.x;
    s.y += a.y + b.y + c.y;
    s.z += a.z + b.z + c.z;
    s.w += a.w + b.w + c.w;
    float4 r;
    r.x = tanhf(s.x); r.y = tanhf(s.y); r.z = tanhf(s.z); r.w = tanhf(s.w);
    *(float4*)(out + i) = r;
}

extern "C" void kernel_launch(void* const* d_in, const int* in_sizes, int n_in,
                              void* d_out, int out_size, void* d_ws, size_t ws_size,
                              hipStream_t stream) {
    const float* enc  = (const float*)d_in[0];
    const float* outp = (const float*)d_in[1];
    // d_in[2] = time_step (unused by the reference math)
    const float* Wa   = (const float*)d_in[3];
    const float* Wp   = (const float*)d_in[4];
    const float* vp   = (const float*)d_in[5];
    const float* Wc   = (const float*)d_in[6];
    float* ws  = (float*)d_ws;
    float* out = (float*)d_out;

    hipLaunchKernelGGL(k1_prep,   dim3(128),  dim3(256), 0, stream, outp, Wa, Wp, ws);
    hipLaunchKernelGGL(k1b_final, dim3(128),  dim3(256), 0, stream, vp, ws);
    hipLaunchKernelGGL(k2_stream, dim3(1024), dim3(256), 0, stream, enc, ws);
    hipLaunchKernelGGL(k3_combine,dim3(64),   dim3(256), 0, stream, outp, ws);
    hipLaunchKernelGGL(k4_gemm,   dim3(256),  dim3(256), 0, stream, Wc, ws);
    hipLaunchKernelGGL(k5_tanh,   dim3(64),   dim3(256), 0, stream, ws, out);
}

// Round 3
// 456.216 us; speedup vs baseline: 1.2287x; 1.0865x over previous
//
#include <hip/hip_runtime.h>
#include <math.h>

#define N_   64
#define L_   1024
#define H_   1024
#define NCH  16

// ws float offsets (no memset needed anywhere — every slot written before read)
#define T_OFF     0          // t[n][h]                    65536
#define PT_OFF    65536      // p_t[n]                     64 (pad 256)
#define TP_OFF    65792      // t partials [gc=16][n][h]   1048576
#define PRAWP_OFF 1114368    // praw partials [hc=16][n][g] 1048576
#define PMZ_OFF   2162944    // (m,Z)[n][ch=16]            2048
#define PC_OFF    2164992    // pc[n][ch][h]               1048576
#define CAT_OFF   3213568    // cat[n][2H]                 131072
// total ~3.34M floats = 13.4 MB

// ---- K1: t-partials = output@W_a (split-g); praw-partials = output@W_p^T (split-h) ----
// 256 blocks: n split in halves for 2x occupancy vs round-2 (acc[32] not acc[64]).
__global__ __launch_bounds__(256) void k1_prep(const float* __restrict__ outp,
                                               const float* __restrict__ Wa,
                                               const float* __restrict__ Wp,
                                               float* __restrict__ ws) {
    float* tp    = ws + TP_OFF;
    float* prawp = ws + PRAWP_OFF;
    const int tid = threadIdx.x;
    const int bid = blockIdx.x;

    float acc[32];
#pragma unroll
    for (int n = 0; n < 32; ++n) acc[n] = 0.f;

    if (bid < 128) {
        // t_p[gc][n][h] = sum_{g in chunk} outp[n,g] * Wa[g,h]
        const int nh = bid & 1;                    // n-half
        const int ht = (bid >> 1) & 3;             // 4 h-tiles
        const int gc = bid >> 3;                   // 16 g-chunks(64)
        const int h  = ht * 256 + tid;
        const int g0c = gc * 64;
        const int nb = nh * 32;
        for (int gq = 0; gq < 16; ++gq) {
            const int g0 = g0c + gq * 4;
            const float w0 = Wa[(size_t)(g0 + 0) * H_ + h];
            const float w1 = Wa[(size_t)(g0 + 1) * H_ + h];
            const float w2 = Wa[(size_t)(g0 + 2) * H_ + h];
            const float w3 = Wa[(size_t)(g0 + 3) * H_ + h];
#pragma unroll
            for (int n = 0; n < 32; ++n) {
                const float4 ov = *(const float4*)(outp + (size_t)(nb + n) * H_ + g0);
                acc[n] = fmaf(ov.x, w0, fmaf(ov.y, w1, fmaf(ov.z, w2, fmaf(ov.w, w3, acc[n]))));
            }
        }
#pragma unroll
        for (int n = 0; n < 32; ++n) tp[((size_t)(gc * 64 + nb + n)) * H_ + h] = acc[n];
    } else {
        // praw_p[hc][n][g] = sum_{h in chunk} outp[n,h] * Wp[g,h]
        const int b = bid - 128;
        const int nh = b & 1;
        const int gt = (b >> 1) & 3;               // 4 g-tiles
        const int hc = b >> 3;                     // 16 h-chunks(64)
        const int g  = gt * 256 + tid;
        const int h0c = hc * 64;
        const int nb = nh * 32;
        for (int hq = 0; hq < 16; ++hq) {
            const int h0 = h0c + hq * 4;
            const float4 wv = *(const float4*)(Wp + (size_t)g * H_ + h0);
#pragma unroll
            for (int n = 0; n < 32; ++n) {
                const float4 ov = *(const float4*)(outp + (size_t)(nb + n) * H_ + h0);
                acc[n] = fmaf(ov.x, wv.x, fmaf(ov.y, wv.y, fmaf(ov.z, wv.z, fmaf(ov.w, wv.w, acc[n]))));
            }
        }
#pragma unroll
        for (int n = 0; n < 32; ++n) prawp[((size_t)(hc * 64 + nb + n)) * H_ + g] = acc[n];
    }
}

// ---- K1b: finalize t[n][h] (sum 16 g-chunks) and p_t[n] (tanh·vp reduce) --------
__global__ __launch_bounds__(256) void k1b_final(const float* __restrict__ vp,
                                                 float* __restrict__ ws) {
    const float* tp    = ws + TP_OFF;
    const float* prawp = ws + PRAWP_OFF;
    float* t  = ws + T_OFF;
    float* pt = ws + PT_OFF;
    const int tid = threadIdx.x;
    const int bid = blockIdx.x;

    if (bid < 64) {
        const int n = bid;
        const int h0 = tid * 4;
        float4 s = make_float4(0, 0, 0, 0);
#pragma unroll
        for (int gc = 0; gc < 16; ++gc) {
            const float4 v = *(const float4*)(tp + ((size_t)(gc * 64 + n)) * H_ + h0);
            s.x += v.x; s.y += v.y; s.z += v.z; s.w += v.w;
        }
        *(float4*)(t + (size_t)n * H_ + h0) = s;
    } else {
        __shared__ float red[256];
        const int n = bid - 64;
        const int g0 = tid * 4;
        float4 s = make_float4(0, 0, 0, 0);
#pragma unroll
        for (int hc = 0; hc < 16; ++hc) {
            const float4 v = *(const float4*)(prawp + ((size_t)(hc * 64 + n)) * H_ + g0);
            s.x += v.x; s.y += v.y; s.z += v.z; s.w += v.w;
        }
        const float4 vv = *(const float4*)(vp + g0);
        float part = tanhf(s.x) * vv.x + tanhf(s.y) * vv.y + tanhf(s.z) * vv.z + tanhf(s.w) * vv.w;
        red[tid] = part;
        __syncthreads();
        for (int st = 128; st > 0; st >>= 1) {
            if (tid < st) red[tid] += red[tid + st];
            __syncthreads();
        }
        if (tid == 0) pt[n] = (float)H_ / (1.f + __expf(-red[0]));
    }
}

// ---- K2: stream enc once, online softmax * gauss, partial contexts --------------
__global__ __launch_bounds__(256, 4) void k2_stream(const float* __restrict__ enc,
                                                    float* __restrict__ ws) {
    __shared__ float Cb[4 * 1024];
    __shared__ float mzs[8];

    const float* t  = ws + T_OFF;
    const float* pt = ws + PT_OFF;
    float* pmz = ws + PMZ_OFF;
    float* pc  = ws + PC_OFF;

    const int tid = threadIdx.x;
    const int bid = blockIdx.x;
    const int n   = bid >> 4;
    const int ch  = bid & 15;
    const int wid = tid >> 6;
    const int j   = tid & 63;

    const float p_t = pt[n];

    // per-lane t fragment (h = k*256 + j*4 + e)
    const float* tb = t + (size_t)n * H_ + j * 4;
    const float4 t0 = *(const float4*)(tb);
    const float4 t1 = *(const float4*)(tb + 256);
    const float4 t2 = *(const float4*)(tb + 512);
    const float4 t3 = *(const float4*)(tb + 768);

    float m = -INFINITY, Z = 0.f;
    float4 C0 = make_float4(0, 0, 0, 0), C1 = C0, C2 = C0, C3 = C0;

    const int l0 = ch * 64 + wid * 16;
    const float* rp = enc + ((size_t)n * L_ + l0) * H_ + j * 4;

    float4 e0 = *(const float4*)(rp);
    float4 e1 = *(const float4*)(rp + 256);
    float4 e2 = *(const float4*)(rp + 512);
    float4 e3 = *(const float4*)(rp + 768);

    for (int i = 0; i < 16; ++i) {
        float4 f0, f1, f2, f3;
        if (i < 15) {  // prefetch next row
            const float* nx = rp + (size_t)(i + 1) * H_;
            f0 = *(const float4*)(nx);
            f1 = *(const float4*)(nx + 256);
            f2 = *(const float4*)(nx + 512);
            f3 = *(const float4*)(nx + 768);
        }
        float pd = e0.x * t0.x;
        pd = fmaf(e0.y, t0.y, pd); pd = fmaf(e0.z, t0.z, pd); pd = fmaf(e0.w, t0.w, pd);
        pd = fmaf(e1.x, t1.x, pd); pd = fmaf(e1.y, t1.y, pd); pd = fmaf(e1.z, t1.z, pd); pd = fmaf(e1.w, t1.w, pd);
        pd = fmaf(e2.x, t2.x, pd); pd = fmaf(e2.y, t2.y, pd); pd = fmaf(e2.z, t2.z, pd); pd = fmaf(e2.w, t2.w, pd);
        pd = fmaf(e3.x, t3.x, pd); pd = fmaf(e3.y, t3.y, pd); pd = fmaf(e3.z, t3.z, pd); pd = fmaf(e3.w, t3.w, pd);
        pd += __shfl_xor(pd, 1, 64);
        pd += __shfl_xor(pd, 2, 64);
        pd += __shfl_xor(pd, 4, 64);
        pd += __shfl_xor(pd, 8, 64);
        pd += __shfl_xor(pd, 16, 64);
        pd += __shfl_xor(pd, 32, 64);

        const int l = l0 + i;
        const float d = (float)l - p_t;
        const float gw = __expf(d * d * (-1.f / 25.f));

        if (pd > m) {  // wave-uniform branch
            const float r = __expf(m - pd);
            Z *= r;
            C0.x *= r; C0.y *= r; C0.z *= r; C0.w *= r;
            C1.x *= r; C1.y *= r; C1.z *= r; C1.w *= r;
            C2.x *= r; C2.y *= r; C2.z *= r; C2.w *= r;
            C3.x *= r; C3.y *= r; C3.z *= r; C3.w *= r;
            m = pd;
        }
        const float e = __expf(pd - m);
        Z += e;
        const float w = e * gw;
        C0.x = fmaf(w, e0.x, C0.x); C0.y = fmaf(w, e0.y, C0.y); C0.z = fmaf(w, e0.z, C0.z); C0.w = fmaf(w, e0.w, C0.w);
        C1.x = fmaf(w, e1.x, C1.x); C1.y = fmaf(w, e1.y, C1.y); C1.z = fmaf(w, e1.z, C1.z); C1.w = fmaf(w, e1.w, C1.w);
        C2.x = fmaf(w, e2.x, C2.x); C2.y = fmaf(w, e2.y, C2.y); C2.z = fmaf(w, e2.z, C2.z); C2.w = fmaf(w, e2.w, C2.w);
        C3.x = fmaf(w, e3.x, C3.x); C3.y = fmaf(w, e3.y, C3.y); C3.z = fmaf(w, e3.z, C3.z); C3.w = fmaf(w, e3.w, C3.w);
        e0 = f0; e1 = f1; e2 = f2; e3 = f3;
    }

    // block combine (4 waves)
    if (j == 0) { mzs[wid * 2] = m; mzs[wid * 2 + 1] = Z; }
    __syncthreads();
    const float mb = fmaxf(fmaxf(mzs[0], mzs[2]), fmaxf(mzs[4], mzs[6]));
    const float sc = __expf(m - mb);
    float* cw = Cb + wid * 1024 + j * 4;
    *(float4*)(cw)       = make_float4(C0.x * sc, C0.y * sc, C0.z * sc, C0.w * sc);
    *(float4*)(cw + 256) = make_float4(C1.x * sc, C1.y * sc, C1.z * sc, C1.w * sc);
    *(float4*)(cw + 512) = make_float4(C2.x * sc, C2.y * sc, C2.z * sc, C2.w * sc);
    *(float4*)(cw + 768) = make_float4(C3.x * sc, C3.y * sc, C3.z * sc, C3.w * sc);
    __syncthreads();
#pragma unroll
    for (int k = 0; k < 4; ++k) {
        const int h = k * 256 + tid;
        const float s = Cb[h] + Cb[1024 + h] + Cb[2048 + h] + Cb[3072 + h];
        pc[((size_t)n * NCH + ch) * H_ + h] = s;
    }
    if (tid == 0) {
        float zb = 0.f;
#pragma unroll
        for (int w2 = 0; w2 < 4; ++w2) zb += mzs[w2 * 2 + 1] * __expf(mzs[w2 * 2] - mb);
        pmz[((size_t)n * NCH + ch) * 2]     = mb;
        pmz[((size_t)n * NCH + ch) * 2 + 1] = zb;
    }
}

// ---- K3: combine chunk partials -> cat = [context, output] ----------------------
__global__ __launch_bounds__(256) void k3_combine(const float* __restrict__ outp,
                                                  float* __restrict__ ws) {
    const float* pmz = ws + PMZ_OFF;
    const float* pc  = ws + PC_OFF;
    float* cat = ws + CAT_OFF;
    const int n = blockIdx.x, tid = threadIdx.x;

    float mv[NCH], zv[NCH], wv[NCH];
    float mt = -INFINITY;
#pragma unroll
    for (int c = 0; c < NCH; ++c) {
        mv[c] = pmz[((size_t)n * NCH + c) * 2];
        zv[c] = pmz[((size_t)n * NCH + c) * 2 + 1];
        mt = fmaxf(mt, mv[c]);
    }
    float zt = 0.f;
#pragma unroll
    for (int c = 0; c < NCH; ++c) { wv[c] = __expf(mv[c] - mt); zt += zv[c] * wv[c]; }
    const float inv = 1.f / zt;
#pragma unroll
    for (int k = 0; k < 4; ++k) {
        const int h = k * 256 + tid;
        float s = 0.f;
#pragma unroll
        for (int c = 0; c < NCH; ++c) s += pc[((size_t)n * NCH + c) * H_ + h] * wv[c];
        cat[(size_t)n * 2048 + h]        = s * inv;
        cat[(size_t)n * 2048 + 1024 + h] = outp[(size_t)n * H_ + h];
    }
}

// ---- K4: out[n,h] = tanh( cat[n,:] . Wc[h,:] )  — fused quarter-combine + tanh --
// Block = one h-group (4 rows); its 4 waves are the 4 c-quarters; combine in LDS.
__global__ __launch_bounds__(256) void k4_fused(const float* __restrict__ Wc,
                                                float* __restrict__ ws,
                                                float* __restrict__ out) {
    __shared__ float qbuf[4][N_][4];   // [quarter][n][r] = 4 KB
    const float* cat = ws + CAT_OFF;
    const int tid = threadIdx.x;
    const int q = tid >> 6, j = tid & 63;   // wave = c-quarter
    const int hg = blockIdx.x;              // 0..255
    const int cs = q * 512 + j * 8;
    const int h0 = hg * 4;

    float4 wA[4], wB[4];
#pragma unroll
    for (int r = 0; r < 4; ++r) {
        const float* wr = Wc + (size_t)(h0 + r) * 2048 + cs;
        wA[r] = *(const float4*)(wr);
        wB[r] = *(const float4*)(wr + 4);
    }
#pragma unroll 2
    for (int n = 0; n < N_; ++n) {
        const float* cr = cat + (size_t)n * 2048 + cs;
        const float4 xA = *(const float4*)(cr);
        const float4 xB = *(const float4*)(cr + 4);
        float d0, d1, d2, d3;
        d0 = xA.x * wA[0].x; d0 = fmaf(xA.y, wA[0].y, d0); d0 = fmaf(xA.z, wA[0].z, d0); d0 = fmaf(xA.w, wA[0].w, d0);
        d0 = fmaf(xB.x, wB[0].x, d0); d0 = fmaf(xB.y, wB[0].y, d0); d0 = fmaf(xB.z, wB[0].z, d0); d0 = fmaf(xB.w, wB[0].w, d0);
        d1 = xA.x * wA[1].x; d1 = fmaf(xA.y, wA[1].y, d1); d1 = fmaf(xA.z, wA[1].z, d1); d1 = fmaf(xA.w, wA[1].w, d1);
        d1 = fmaf(xB.x, wB[1].x, d1); d1 = fmaf(xB.y, wB[1].y, d1); d1 = fmaf(xB.z, wB[1].z, d1); d1 = fmaf(xB.w, wB[1].w, d1);
        d2 = xA.x * wA[2].x; d2 = fmaf(xA.y, wA[2].y, d2); d2 = fmaf(xA.z, wA[2].z, d2); d2 = fmaf(xA.w, wA[2].w, d2);
        d2 = fmaf(xB.x, wB[2].x, d2); d2 = fmaf(xB.y, wB[2].y, d2); d2 = fmaf(xB.z, wB[2].z, d2); d2 = fmaf(xB.w, wB[2].w, d2);
        d3 = xA.x * wA[3].x; d3 = fmaf(xA.y, wA[3].y, d3); d3 = fmaf(xA.z, wA[3].z, d3); d3 = fmaf(xA.w, wA[3].w, d3);
        d3 = fmaf(xB.x, wB[3].x, d3); d3 = fmaf(xB.y, wB[3].y, d3); d3 = fmaf(xB.z, wB[3].z, d3); d3 = fmaf(xB.w, wB[3].w, d3);
#pragma unroll
        for (int msk = 1; msk < 64; msk <<= 1) {
            d0 += __shfl_xor(d0, msk, 64);
            d1 += __shfl_xor(d1, msk, 64);
            d2 += __shfl_xor(d2, msk, 64);
            d3 += __shfl_xor(d3, msk, 64);
        }
        if (j == 0) *(float4*)&qbuf[q][n][0] = make_float4(d0, d1, d2, d3);
    }
    __syncthreads();
    // 256 threads: one (n, r) each; sum 4 quarters, tanh, store.
    const int n = tid >> 2, r = tid & 3;
    const float s = qbuf[0][n][r] + qbuf[1][n][r] + qbuf[2][n][r] + qbuf[3][n][r];
    out[(size_t)n * H_ + h0 + r] = tanhf(s);
}

extern "C" void kernel_launch(void* const* d_in, const int* in_sizes, int n_in,
                              void* d_out, int out_size, void* d_ws, size_t ws_size,
                              hipStream_t stream) {
    const float* enc  = (const float*)d_in[0];
    const float* outp = (const float*)d_in[1];
    // d_in[2] = time_step (unused by the reference math)
    const float* Wa   = (const float*)d_in[3];
    const float* Wp   = (const float*)d_in[4];
    const float* vp   = (const float*)d_in[5];
    const float* Wc   = (const float*)d_in[6];
    float* ws  = (float*)d_ws;
    float* out = (float*)d_out;

    hipLaunchKernelGGL(k1_prep,   dim3(256),  dim3(256), 0, stream, outp, Wa, Wp, ws);
    hipLaunchKernelGGL(k1b_final, dim3(128),  dim3(256), 0, stream, vp, ws);
    hipLaunchKernelGGL(k2_stream, dim3(1024), dim3(256), 0, stream, enc, ws);
    hipLaunchKernelGGL(k3_combine,dim3(64),   dim3(256), 0, stream, outp, ws);
    hipLaunchKernelGGL(k4_fused,  dim3(256),  dim3(256), 0, stream, Wc, ws, out);
}

// Round 4
// 424.734 us; speedup vs baseline: 1.3198x; 1.0741x over previous
//
#include <hip/hip_runtime.h>
#include <math.h>

#define N_   64
#define L_   1024
#define H_   1024
#define NCH  16

// ws float offsets (no memset needed anywhere — every slot written before read)
#define T_OFF     0          // t[n][h]                    65536
#define PT_OFF    65536      // p_t[n]                     64 (pad 256)
#define TP_OFF    65792      // t partials [gc=16][n][h]   1048576
#define PRAWP_OFF 1114368    // praw partials [hc=16][n][g] 1048576
#define PMZ_OFF   2162944    // (m,Z)[n][ch=16]            2048
#define PC_OFF    2164992    // pc[n][ch][h]               1048576
#define CAT_OFF   3213568    // cat[n][2H]                 131072
// total ~3.34M floats = 13.4 MB

// ---- K1: t-partials = output@W_a (split-g); praw-partials = output@W_p^T (split-h) ----
// 512 blocks = 2 blocks/CU (n split in quarters, acc[16]): latency hiding for the
// uniform outp loads + weight row loads. Weight duplication (x4) is L3-served.
__global__ __launch_bounds__(256) void k1_prep(const float* __restrict__ outp,
                                               const float* __restrict__ Wa,
                                               const float* __restrict__ Wp,
                                               float* __restrict__ ws) {
    float* tp    = ws + TP_OFF;
    float* prawp = ws + PRAWP_OFF;
    const int tid = threadIdx.x;
    const int bid = blockIdx.x;

    float acc[16];
#pragma unroll
    for (int n = 0; n < 16; ++n) acc[n] = 0.f;

    if (bid < 256) {
        // t_p[gc][n][h] = sum_{g in chunk} outp[n,g] * Wa[g,h]
        const int nq = bid & 3;                    // n-quarter (16 n)
        const int ht = (bid >> 2) & 3;             // 4 h-tiles
        const int gc = bid >> 4;                   // 16 g-chunks(64)
        const int h  = ht * 256 + tid;
        const int g0c = gc * 64;
        const int nb = nq * 16;
        for (int gq = 0; gq < 16; ++gq) {
            const int g0 = g0c + gq * 4;
            const float w0 = Wa[(size_t)(g0 + 0) * H_ + h];
            const float w1 = Wa[(size_t)(g0 + 1) * H_ + h];
            const float w2 = Wa[(size_t)(g0 + 2) * H_ + h];
            const float w3 = Wa[(size_t)(g0 + 3) * H_ + h];
#pragma unroll
            for (int n = 0; n < 16; ++n) {
                const float4 ov = *(const float4*)(outp + (size_t)(nb + n) * H_ + g0);
                acc[n] = fmaf(ov.x, w0, fmaf(ov.y, w1, fmaf(ov.z, w2, fmaf(ov.w, w3, acc[n]))));
            }
        }
#pragma unroll
        for (int n = 0; n < 16; ++n) tp[((size_t)(gc * 64 + nb + n)) * H_ + h] = acc[n];
    } else {
        // praw_p[hc][n][g] = sum_{h in chunk} outp[n,h] * Wp[g,h]
        const int b = bid - 256;
        const int nq = b & 3;
        const int gt = (b >> 2) & 3;               // 4 g-tiles
        const int hc = b >> 4;                     // 16 h-chunks(64)
        const int g  = gt * 256 + tid;
        const int h0c = hc * 64;
        const int nb = nq * 16;
        for (int hq = 0; hq < 16; ++hq) {
            const int h0 = h0c + hq * 4;
            const float4 wv = *(const float4*)(Wp + (size_t)g * H_ + h0);
#pragma unroll
            for (int n = 0; n < 16; ++n) {
                const float4 ov = *(const float4*)(outp + (size_t)(nb + n) * H_ + h0);
                acc[n] = fmaf(ov.x, wv.x, fmaf(ov.y, wv.y, fmaf(ov.z, wv.z, fmaf(ov.w, wv.w, acc[n]))));
            }
        }
#pragma unroll
        for (int n = 0; n < 16; ++n) prawp[((size_t)(hc * 64 + nb + n)) * H_ + g] = acc[n];
    }
}

// ---- K1b: finalize t[n][h] (sum 16 g-chunks) and p_t[n] (tanh·vp reduce) --------
__global__ __launch_bounds__(256) void k1b_final(const float* __restrict__ vp,
                                                 float* __restrict__ ws) {
    const float* tp    = ws + TP_OFF;
    const float* prawp = ws + PRAWP_OFF;
    float* t  = ws + T_OFF;
    float* pt = ws + PT_OFF;
    const int tid = threadIdx.x;
    const int bid = blockIdx.x;

    if (bid < 64) {
        const int n = bid;
        const int h0 = tid * 4;
        float4 s = make_float4(0, 0, 0, 0);
#pragma unroll
        for (int gc = 0; gc < 16; ++gc) {
            const float4 v = *(const float4*)(tp + ((size_t)(gc * 64 + n)) * H_ + h0);
            s.x += v.x; s.y += v.y; s.z += v.z; s.w += v.w;
        }
        *(float4*)(t + (size_t)n * H_ + h0) = s;
    } else {
        __shared__ float red[256];
        const int n = bid - 64;
        const int g0 = tid * 4;
        float4 s = make_float4(0, 0, 0, 0);
#pragma unroll
        for (int hc = 0; hc < 16; ++hc) {
            const float4 v = *(const float4*)(prawp + ((size_t)(hc * 64 + n)) * H_ + g0);
            s.x += v.x; s.y += v.y; s.z += v.z; s.w += v.w;
        }
        const float4 vv = *(const float4*)(vp + g0);
        float part = tanhf(s.x) * vv.x + tanhf(s.y) * vv.y + tanhf(s.z) * vv.z + tanhf(s.w) * vv.w;
        red[tid] = part;
        __syncthreads();
        for (int st = 128; st > 0; st >>= 1) {
            if (tid < st) red[tid] += red[tid + st];
            __syncthreads();
        }
        if (tid == 0) pt[n] = (float)H_ / (1.f + __expf(-red[0]));
    }
}

// ---- K2: stream enc once, online softmax * gauss, partial contexts --------------
__global__ __launch_bounds__(256, 4) void k2_stream(const float* __restrict__ enc,
                                                    float* __restrict__ ws) {
    __shared__ float Cb[4 * 1024];
    __shared__ float mzs[8];

    const float* t  = ws + T_OFF;
    const float* pt = ws + PT_OFF;
    float* pmz = ws + PMZ_OFF;
    float* pc  = ws + PC_OFF;

    const int tid = threadIdx.x;
    const int bid = blockIdx.x;
    const int n   = bid >> 4;
    const int ch  = bid & 15;
    const int wid = tid >> 6;
    const int j   = tid & 63;

    const float p_t = pt[n];

    // per-lane t fragment (h = k*256 + j*4 + e)
    const float* tb = t + (size_t)n * H_ + j * 4;
    const float4 t0 = *(const float4*)(tb);
    const float4 t1 = *(const float4*)(tb + 256);
    const float4 t2 = *(const float4*)(tb + 512);
    const float4 t3 = *(const float4*)(tb + 768);

    float m = -INFINITY, Z = 0.f;
    float4 C0 = make_float4(0, 0, 0, 0), C1 = C0, C2 = C0, C3 = C0;

    const int l0 = ch * 64 + wid * 16;
    const float* rp = enc + ((size_t)n * L_ + l0) * H_ + j * 4;

    float4 e0 = *(const float4*)(rp);
    float4 e1 = *(const float4*)(rp + 256);
    float4 e2 = *(const float4*)(rp + 512);
    float4 e3 = *(const float4*)(rp + 768);

    for (int i = 0; i < 16; ++i) {
        float4 f0, f1, f2, f3;
        if (i < 15) {  // prefetch next row
            const float* nx = rp + (size_t)(i + 1) * H_;
            f0 = *(const float4*)(nx);
            f1 = *(const float4*)(nx + 256);
            f2 = *(const float4*)(nx + 512);
            f3 = *(const float4*)(nx + 768);
        }
        float pd = e0.x * t0.x;
        pd = fmaf(e0.y, t0.y, pd); pd = fmaf(e0.z, t0.z, pd); pd = fmaf(e0.w, t0.w, pd);
        pd = fmaf(e1.x, t1.x, pd); pd = fmaf(e1.y, t1.y, pd); pd = fmaf(e1.z, t1.z, pd); pd = fmaf(e1.w, t1.w, pd);
        pd = fmaf(e2.x, t2.x, pd); pd = fmaf(e2.y, t2.y, pd); pd = fmaf(e2.z, t2.z, pd); pd = fmaf(e2.w, t2.w, pd);
        pd = fmaf(e3.x, t3.x, pd); pd = fmaf(e3.y, t3.y, pd); pd = fmaf(e3.z, t3.z, pd); pd = fmaf(e3.w, t3.w, pd);
        pd += __shfl_xor(pd, 1, 64);
        pd += __shfl_xor(pd, 2, 64);
        pd += __shfl_xor(pd, 4, 64);
        pd += __shfl_xor(pd, 8, 64);
        pd += __shfl_xor(pd, 16, 64);
        pd += __shfl_xor(pd, 32, 64);

        const int l = l0 + i;
        const float d = (float)l - p_t;
        const float gw = __expf(d * d * (-1.f / 25.f));

        if (pd > m) {  // wave-uniform branch
            const float r = __expf(m - pd);
            Z *= r;
            C0.x *= r; C0.y *= r; C0.z *= r; C0.w *= r;
            C1.x *= r; C1.y *= r; C1.z *= r; C1.w *= r;
            C2.x *= r; C2.y *= r; C2.z *= r; C2.w *= r;
            C3.x *= r; C3.y *= r; C3.z *= r; C3.w *= r;
            m = pd;
        }
        const float e = __expf(pd - m);
        Z += e;
        const float w = e * gw;
        C0.x = fmaf(w, e0.x, C0.x); C0.y = fmaf(w, e0.y, C0.y); C0.z = fmaf(w, e0.z, C0.z); C0.w = fmaf(w, e0.w, C0.w);
        C1.x = fmaf(w, e1.x, C1.x); C1.y = fmaf(w, e1.y, C1.y); C1.z = fmaf(w, e1.z, C1.z); C1.w = fmaf(w, e1.w, C1.w);
        C2.x = fmaf(w, e2.x, C2.x); C2.y = fmaf(w, e2.y, C2.y); C2.z = fmaf(w, e2.z, C2.z); C2.w = fmaf(w, e2.w, C2.w);
        C3.x = fmaf(w, e3.x, C3.x); C3.y = fmaf(w, e3.y, C3.y); C3.z = fmaf(w, e3.z, C3.z); C3.w = fmaf(w, e3.w, C3.w);
        e0 = f0; e1 = f1; e2 = f2; e3 = f3;
    }

    // block combine (4 waves)
    if (j == 0) { mzs[wid * 2] = m; mzs[wid * 2 + 1] = Z; }
    __syncthreads();
    const float mb = fmaxf(fmaxf(mzs[0], mzs[2]), fmaxf(mzs[4], mzs[6]));
    const float sc = __expf(m - mb);
    float* cw = Cb + wid * 1024 + j * 4;
    *(float4*)(cw)       = make_float4(C0.x * sc, C0.y * sc, C0.z * sc, C0.w * sc);
    *(float4*)(cw + 256) = make_float4(C1.x * sc, C1.y * sc, C1.z * sc, C1.w * sc);
    *(float4*)(cw + 512) = make_float4(C2.x * sc, C2.y * sc, C2.z * sc, C2.w * sc);
    *(float4*)(cw + 768) = make_float4(C3.x * sc, C3.y * sc, C3.z * sc, C3.w * sc);
    __syncthreads();
#pragma unroll
    for (int k = 0; k < 4; ++k) {
        const int h = k * 256 + tid;
        const float s = Cb[h] + Cb[1024 + h] + Cb[2048 + h] + Cb[3072 + h];
        pc[((size_t)n * NCH + ch) * H_ + h] = s;
    }
    if (tid == 0) {
        float zb = 0.f;
#pragma unroll
        for (int w2 = 0; w2 < 4; ++w2) zb += mzs[w2 * 2 + 1] * __expf(mzs[w2 * 2] - mb);
        pmz[((size_t)n * NCH + ch) * 2]     = mb;
        pmz[((size_t)n * NCH + ch) * 2 + 1] = zb;
    }
}

// ---- K3: combine chunk partials -> cat = [context, output] ----------------------
__global__ __launch_bounds__(256) void k3_combine(const float* __restrict__ outp,
                                                  float* __restrict__ ws) {
    const float* pmz = ws + PMZ_OFF;
    const float* pc  = ws + PC_OFF;
    float* cat = ws + CAT_OFF;
    const int n = blockIdx.x, tid = threadIdx.x;

    float mv[NCH], zv[NCH], wv[NCH];
    float mt = -INFINITY;
#pragma unroll
    for (int c = 0; c < NCH; ++c) {
        mv[c] = pmz[((size_t)n * NCH + c) * 2];
        zv[c] = pmz[((size_t)n * NCH + c) * 2 + 1];
        mt = fmaxf(mt, mv[c]);
    }
    float zt = 0.f;
#pragma unroll
    for (int c = 0; c < NCH; ++c) { wv[c] = __expf(mv[c] - mt); zt += zv[c] * wv[c]; }
    const float inv = 1.f / zt;
#pragma unroll
    for (int k = 0; k < 4; ++k) {
        const int h = k * 256 + tid;
        float s = 0.f;
#pragma unroll
        for (int c = 0; c < NCH; ++c) s += pc[((size_t)n * NCH + c) * H_ + h] * wv[c];
        cat[(size_t)n * 2048 + h]        = s * inv;
        cat[(size_t)n * 2048 + 1024 + h] = outp[(size_t)n * H_ + h];
    }
}

// ---- K4: out[n,h] = tanh( cat[n,:] . Wc[h,:] )  — fused quarter-combine + tanh --
// 512 blocks = 2 blocks/CU: block = (h-group, n-half); 4 waves = 4 c-quarters.
__global__ __launch_bounds__(256) void k4_fused(const float* __restrict__ Wc,
                                                float* __restrict__ ws,
                                                float* __restrict__ out) {
    __shared__ float qbuf[4][32][4];   // [quarter][n][r] = 2 KB
    const float* cat = ws + CAT_OFF;
    const int tid = threadIdx.x;
    const int q = tid >> 6, j = tid & 63;   // wave = c-quarter
    const int hg = blockIdx.x >> 1;         // 0..255
    const int nb = (blockIdx.x & 1) * 32;   // n-half
    const int cs = q * 512 + j * 8;
    const int h0 = hg * 4;

    float4 wA[4], wB[4];
#pragma unroll
    for (int r = 0; r < 4; ++r) {
        const float* wr = Wc + (size_t)(h0 + r) * 2048 + cs;
        wA[r] = *(const float4*)(wr);
        wB[r] = *(const float4*)(wr + 4);
    }
#pragma unroll 2
    for (int n = 0; n < 32; ++n) {
        const float* cr = cat + (size_t)(nb + n) * 2048 + cs;
        const float4 xA = *(const float4*)(cr);
        const float4 xB = *(const float4*)(cr + 4);
        float d0, d1, d2, d3;
        d0 = xA.x * wA[0].x; d0 = fmaf(xA.y, wA[0].y, d0); d0 = fmaf(xA.z, wA[0].z, d0); d0 = fmaf(xA.w, wA[0].w, d0);
        d0 = fmaf(xB.x, wB[0].x, d0); d0 = fmaf(xB.y, wB[0].y, d0); d0 = fmaf(xB.z, wB[0].z, d0); d0 = fmaf(xB.w, wB[0].w, d0);
        d1 = xA.x * wA[1].x; d1 = fmaf(xA.y, wA[1].y, d1); d1 = fmaf(xA.z, wA[1].z, d1); d1 = fmaf(xA.w, wA[1].w, d1);
        d1 = fmaf(xB.x, wB[1].x, d1); d1 = fmaf(xB.y, wB[1].y, d1); d1 = fmaf(xB.z, wB[1].z, d1); d1 = fmaf(xB.w, wB[1].w, d1);
        d2 = xA.x * wA[2].x; d2 = fmaf(xA.y, wA[2].y, d2); d2 = fmaf(xA.z, wA[2].z, d2); d2 = fmaf(xA.w, wA[2].w, d2);
        d2 = fmaf(xB.x, wB[2].x, d2); d2 = fmaf(xB.y, wB[2].y, d2); d2 = fmaf(xB.z, wB[2].z, d2); d2 = fmaf(xB.w, wB[2].w, d2);
        d3 = xA.x * wA[3].x; d3 = fmaf(xA.y, wA[3].y, d3); d3 = fmaf(xA.z, wA[3].z, d3); d3 = fmaf(xA.w, wA[3].w, d3);
        d3 = fmaf(xB.x, wB[3].x, d3); d3 = fmaf(xB.y, wB[3].y, d3); d3 = fmaf(xB.z, wB[3].z, d3); d3 = fmaf(xB.w, wB[3].w, d3);
#pragma unroll
        for (int msk = 1; msk < 64; msk <<= 1) {
            d0 += __shfl_xor(d0, msk, 64);
            d1 += __shfl_xor(d1, msk, 64);
            d2 += __shfl_xor(d2, msk, 64);
            d3 += __shfl_xor(d3, msk, 64);
        }
        if (j == 0) *(float4*)&qbuf[q][n][0] = make_float4(d0, d1, d2, d3);
    }
    __syncthreads();
    // 128 threads: one (n, r) each; sum 4 quarters, tanh, store.
    if (tid < 128) {
        const int n = tid >> 2, r = tid & 3;
        const float s = qbuf[0][n][r] + qbuf[1][n][r] + qbuf[2][n][r] + qbuf[3][n][r];
        out[(size_t)(nb + n) * H_ + h0 + r] = tanhf(s);
    }
}

extern "C" void kernel_launch(void* const* d_in, const int* in_sizes, int n_in,
                              void* d_out, int out_size, void* d_ws, size_t ws_size,
                              hipStream_t stream) {
    const float* enc  = (const float*)d_in[0];
    const float* outp = (const float*)d_in[1];
    // d_in[2] = time_step (unused by the reference math)
    const float* Wa   = (const float*)d_in[3];
    const float* Wp   = (const float*)d_in[4];
    const float* vp   = (const float*)d_in[5];
    const float* Wc   = (const float*)d_in[6];
    float* ws  = (float*)d_ws;
    float* out = (float*)d_out;

    hipLaunchKernelGGL(k1_prep,   dim3(512),  dim3(256), 0, stream, outp, Wa, Wp, ws);
    hipLaunchKernelGGL(k1b_final, dim3(128),  dim3(256), 0, stream, vp, ws);
    hipLaunchKernelGGL(k2_stream, dim3(1024), dim3(256), 0, stream, enc, ws);
    hipLaunchKernelGGL(k3_combine,dim3(64),   dim3(256), 0, stream, outp, ws);
    hipLaunchKernelGGL(k4_fused,  dim3(512),  dim3(256), 0, stream, Wc, ws, out);
}

// Round 5
// 424.530 us; speedup vs baseline: 1.3204x; 1.0005x over previous
//
#include <hip/hip_runtime.h>
#include <math.h>

#define N_   64
#define L_   1024
#define H_   1024
#define NCH  16

// ws float offsets (no memset needed anywhere — every slot written before read)
#define T_OFF     0          // t[n][h]                    65536
#define PT_OFF    65536      // p_t[n]                     64 (pad 256)
#define TP_OFF    65792      // t partials [gc=16][n][h]   1048576
#define PRAWP_OFF 1114368    // praw partials [hc=16][n][g] 1048576
#define PMZ_OFF   2162944    // (m,Z)[n][ch=16]            2048
#define PC_OFF    2164992    // pc[n][ch][h]               1048576
#define CAT_OFF   3213568    // cat[n][2H]                 131072
// total ~3.34M floats = 13.4 MB

// ---- K1: t-partials = output@W_a (split-g); praw-partials = output@W_p^T (split-h) ----
// 1024 blocks = 4 blocks/CU (n split in eighths, acc[8]). Weight duplication (x8)
// is served by the 256 MiB L3.
__global__ __launch_bounds__(256) void k1_prep(const float* __restrict__ outp,
                                               const float* __restrict__ Wa,
                                               const float* __restrict__ Wp,
                                               float* __restrict__ ws) {
    float* tp    = ws + TP_OFF;
    float* prawp = ws + PRAWP_OFF;
    const int tid = threadIdx.x;
    const int bid = blockIdx.x;

    float acc[8];
#pragma unroll
    for (int n = 0; n < 8; ++n) acc[n] = 0.f;

    if (bid < 512) {
        // t_p[gc][n][h] = sum_{g in chunk} outp[n,g] * Wa[g,h]
        const int nq = bid & 7;                    // n-eighth (8 n)
        const int ht = (bid >> 3) & 3;             // 4 h-tiles
        const int gc = bid >> 5;                   // 16 g-chunks(64)
        const int h  = ht * 256 + tid;
        const int g0c = gc * 64;
        const int nb = nq * 8;
        for (int gq = 0; gq < 16; ++gq) {
            const int g0 = g0c + gq * 4;
            const float w0 = Wa[(size_t)(g0 + 0) * H_ + h];
            const float w1 = Wa[(size_t)(g0 + 1) * H_ + h];
            const float w2 = Wa[(size_t)(g0 + 2) * H_ + h];
            const float w3 = Wa[(size_t)(g0 + 3) * H_ + h];
#pragma unroll
            for (int n = 0; n < 8; ++n) {
                const float4 ov = *(const float4*)(outp + (size_t)(nb + n) * H_ + g0);
                acc[n] = fmaf(ov.x, w0, fmaf(ov.y, w1, fmaf(ov.z, w2, fmaf(ov.w, w3, acc[n]))));
            }
        }
#pragma unroll
        for (int n = 0; n < 8; ++n) tp[((size_t)(gc * 64 + nb + n)) * H_ + h] = acc[n];
    } else {
        // praw_p[hc][n][g] = sum_{h in chunk} outp[n,h] * Wp[g,h]
        const int b = bid - 512;
        const int nq = b & 7;
        const int gt = (b >> 3) & 3;               // 4 g-tiles
        const int hc = b >> 5;                     // 16 h-chunks(64)
        const int g  = gt * 256 + tid;
        const int h0c = hc * 64;
        const int nb = nq * 8;
        for (int hq = 0; hq < 16; ++hq) {
            const int h0 = h0c + hq * 4;
            const float4 wv = *(const float4*)(Wp + (size_t)g * H_ + h0);
#pragma unroll
            for (int n = 0; n < 8; ++n) {
                const float4 ov = *(const float4*)(outp + (size_t)(nb + n) * H_ + h0);
                acc[n] = fmaf(ov.x, wv.x, fmaf(ov.y, wv.y, fmaf(ov.z, wv.z, fmaf(ov.w, wv.w, acc[n]))));
            }
        }
#pragma unroll
        for (int n = 0; n < 8; ++n) prawp[((size_t)(hc * 64 + nb + n)) * H_ + g] = acc[n];
    }
}

// ---- K1b: finalize t[n][h] (sum 16 g-chunks) and p_t[n] (tanh·vp reduce) --------
__global__ __launch_bounds__(256) void k1b_final(const float* __restrict__ vp,
                                                 float* __restrict__ ws) {
    const float* tp    = ws + TP_OFF;
    const float* prawp = ws + PRAWP_OFF;
    float* t  = ws + T_OFF;
    float* pt = ws + PT_OFF;
    const int tid = threadIdx.x;
    const int bid = blockIdx.x;

    if (bid < 64) {
        const int n = bid;
        const int h0 = tid * 4;
        float4 s = make_float4(0, 0, 0, 0);
#pragma unroll
        for (int gc = 0; gc < 16; ++gc) {
            const float4 v = *(const float4*)(tp + ((size_t)(gc * 64 + n)) * H_ + h0);
            s.x += v.x; s.y += v.y; s.z += v.z; s.w += v.w;
        }
        *(float4*)(t + (size_t)n * H_ + h0) = s;
    } else {
        __shared__ float red[256];
        const int n = bid - 64;
        const int g0 = tid * 4;
        float4 s = make_float4(0, 0, 0, 0);
#pragma unroll
        for (int hc = 0; hc < 16; ++hc) {
            const float4 v = *(const float4*)(prawp + ((size_t)(hc * 64 + n)) * H_ + g0);
            s.x += v.x; s.y += v.y; s.z += v.z; s.w += v.w;
        }
        const float4 vv = *(const float4*)(vp + g0);
        float part = tanhf(s.x) * vv.x + tanhf(s.y) * vv.y + tanhf(s.z) * vv.z + tanhf(s.w) * vv.w;
        red[tid] = part;
        __syncthreads();
        for (int st = 128; st > 0; st >>= 1) {
            if (tid < st) red[tid] += red[tid + st];
            __syncthreads();
        }
        if (tid == 0) pt[n] = (float)H_ / (1.f + __expf(-red[0]));
    }
}

// ---- K2: stream enc once, online softmax * gauss, partial contexts --------------
__global__ __launch_bounds__(256, 4) void k2_stream(const float* __restrict__ enc,
                                                    float* __restrict__ ws) {
    __shared__ float Cb[4 * 1024];
    __shared__ float mzs[8];

    const float* t  = ws + T_OFF;
    const float* pt = ws + PT_OFF;
    float* pmz = ws + PMZ_OFF;
    float* pc  = ws + PC_OFF;

    const int tid = threadIdx.x;
    const int bid = blockIdx.x;
    const int n   = bid >> 4;
    const int ch  = bid & 15;
    const int wid = tid >> 6;
    const int j   = tid & 63;

    const float p_t = pt[n];

    // per-lane t fragment (h = k*256 + j*4 + e)
    const float* tb = t + (size_t)n * H_ + j * 4;
    const float4 t0 = *(const float4*)(tb);
    const float4 t1 = *(const float4*)(tb + 256);
    const float4 t2 = *(const float4*)(tb + 512);
    const float4 t3 = *(const float4*)(tb + 768);

    float m = -INFINITY, Z = 0.f;
    float4 C0 = make_float4(0, 0, 0, 0), C1 = C0, C2 = C0, C3 = C0;

    const int l0 = ch * 64 + wid * 16;
    const float* rp = enc + ((size_t)n * L_ + l0) * H_ + j * 4;

    float4 e0 = *(const float4*)(rp);
    float4 e1 = *(const float4*)(rp + 256);
    float4 e2 = *(const float4*)(rp + 512);
    float4 e3 = *(const float4*)(rp + 768);

    for (int i = 0; i < 16; ++i) {
        float4 f0, f1, f2, f3;
        if (i < 15) {  // prefetch next row
            const float* nx = rp + (size_t)(i + 1) * H_;
            f0 = *(const float4*)(nx);
            f1 = *(const float4*)(nx + 256);
            f2 = *(const float4*)(nx + 512);
            f3 = *(const float4*)(nx + 768);
        }
        float pd = e0.x * t0.x;
        pd = fmaf(e0.y, t0.y, pd); pd = fmaf(e0.z, t0.z, pd); pd = fmaf(e0.w, t0.w, pd);
        pd = fmaf(e1.x, t1.x, pd); pd = fmaf(e1.y, t1.y, pd); pd = fmaf(e1.z, t1.z, pd); pd = fmaf(e1.w, t1.w, pd);
        pd = fmaf(e2.x, t2.x, pd); pd = fmaf(e2.y, t2.y, pd); pd = fmaf(e2.z, t2.z, pd); pd = fmaf(e2.w, t2.w, pd);
        pd = fmaf(e3.x, t3.x, pd); pd = fmaf(e3.y, t3.y, pd); pd = fmaf(e3.z, t3.z, pd); pd = fmaf(e3.w, t3.w, pd);
        pd += __shfl_xor(pd, 1, 64);
        pd += __shfl_xor(pd, 2, 64);
        pd += __shfl_xor(pd, 4, 64);
        pd += __shfl_xor(pd, 8, 64);
        pd += __shfl_xor(pd, 16, 64);
        pd += __shfl_xor(pd, 32, 64);

        const int l = l0 + i;
        const float d = (float)l - p_t;
        const float gw = __expf(d * d * (-1.f / 25.f));

        if (pd > m) {  // wave-uniform branch
            const float r = __expf(m - pd);
            Z *= r;
            C0.x *= r; C0.y *= r; C0.z *= r; C0.w *= r;
            C1.x *= r; C1.y *= r; C1.z *= r; C1.w *= r;
            C2.x *= r; C2.y *= r; C2.z *= r; C2.w *= r;
            C3.x *= r; C3.y *= r; C3.z *= r; C3.w *= r;
            m = pd;
        }
        const float e = __expf(pd - m);
        Z += e;
        const float w = e * gw;
        C0.x = fmaf(w, e0.x, C0.x); C0.y = fmaf(w, e0.y, C0.y); C0.z = fmaf(w, e0.z, C0.z); C0.w = fmaf(w, e0.w, C0.w);
        C1.x = fmaf(w, e1.x, C1.x); C1.y = fmaf(w, e1.y, C1.y); C1.z = fmaf(w, e1.z, C1.z); C1.w = fmaf(w, e1.w, C1.w);
        C2.x = fmaf(w, e2.x, C2.x); C2.y = fmaf(w, e2.y, C2.y); C2.z = fmaf(w, e2.z, C2.z); C2.w = fmaf(w, e2.w, C2.w);
        C3.x = fmaf(w, e3.x, C3.x); C3.y = fmaf(w, e3.y, C3.y); C3.z = fmaf(w, e3.z, C3.z); C3.w = fmaf(w, e3.w, C3.w);
        e0 = f0; e1 = f1; e2 = f2; e3 = f3;
    }

    // block combine (4 waves)
    if (j == 0) { mzs[wid * 2] = m; mzs[wid * 2 + 1] = Z; }
    __syncthreads();
    const float mb = fmaxf(fmaxf(mzs[0], mzs[2]), fmaxf(mzs[4], mzs[6]));
    const float sc = __expf(m - mb);
    float* cw = Cb + wid * 1024 + j * 4;
    *(float4*)(cw)       = make_float4(C0.x * sc, C0.y * sc, C0.z * sc, C0.w * sc);
    *(float4*)(cw + 256) = make_float4(C1.x * sc, C1.y * sc, C1.z * sc, C1.w * sc);
    *(float4*)(cw + 512) = make_float4(C2.x * sc, C2.y * sc, C2.z * sc, C2.w * sc);
    *(float4*)(cw + 768) = make_float4(C3.x * sc, C3.y * sc, C3.z * sc, C3.w * sc);
    __syncthreads();
#pragma unroll
    for (int k = 0; k < 4; ++k) {
        const int h = k * 256 + tid;
        const float s = Cb[h] + Cb[1024 + h] + Cb[2048 + h] + Cb[3072 + h];
        pc[((size_t)n * NCH + ch) * H_ + h] = s;
    }
    if (tid == 0) {
        float zb = 0.f;
#pragma unroll
        for (int w2 = 0; w2 < 4; ++w2) zb += mzs[w2 * 2 + 1] * __expf(mzs[w2 * 2] - mb);
        pmz[((size_t)n * NCH + ch) * 2]     = mb;
        pmz[((size_t)n * NCH + ch) * 2 + 1] = zb;
    }
}

// ---- K3: combine chunk partials -> cat = [context, output] ----------------------
// 256 blocks: block = (n, h-quarter); pmz re-read per block is L1/L2-trivial.
__global__ __launch_bounds__(256) void k3_combine(const float* __restrict__ outp,
                                                  float* __restrict__ ws) {
    const float* pmz = ws + PMZ_OFF;
    const float* pc  = ws + PC_OFF;
    float* cat = ws + CAT_OFF;
    const int n = blockIdx.x >> 2, kq = blockIdx.x & 3, tid = threadIdx.x;

    float mv[NCH], zv[NCH], wv[NCH];
    float mt = -INFINITY;
#pragma unroll
    for (int c = 0; c < NCH; ++c) {
        mv[c] = pmz[((size_t)n * NCH + c) * 2];
        zv[c] = pmz[((size_t)n * NCH + c) * 2 + 1];
        mt = fmaxf(mt, mv[c]);
    }
    float zt = 0.f;
#pragma unroll
    for (int c = 0; c < NCH; ++c) { wv[c] = __expf(mv[c] - mt); zt += zv[c] * wv[c]; }
    const float inv = 1.f / zt;
    const int h = kq * 256 + tid;
    float s = 0.f;
#pragma unroll
    for (int c = 0; c < NCH; ++c) s += pc[((size_t)n * NCH + c) * H_ + h] * wv[c];
    cat[(size_t)n * 2048 + h]        = s * inv;
    cat[(size_t)n * 2048 + 1024 + h] = outp[(size_t)n * H_ + h];
}

// ---- K4: out[n,h] = tanh( cat[n,:] . Wc[h,:] )  — fused quarter-combine + tanh --
// 1024 blocks = 4 blocks/CU: block = (h-group, n-quarter); 4 waves = 4 c-quarters.
__global__ __launch_bounds__(256) void k4_fused(const float* __restrict__ Wc,
                                                float* __restrict__ ws,
                                                float* __restrict__ out) {
    __shared__ float qbuf[4][16][4];   // [quarter][n][r] = 1 KB
    const float* cat = ws + CAT_OFF;
    const int tid = threadIdx.x;
    const int q = tid >> 6, j = tid & 63;   // wave = c-quarter
    const int hg = blockIdx.x >> 2;         // 0..255
    const int nb = (blockIdx.x & 3) * 16;   // n-quarter
    const int cs = q * 512 + j * 8;
    const int h0 = hg * 4;

    float4 wA[4], wB[4];
#pragma unroll
    for (int r = 0; r < 4; ++r) {
        const float* wr = Wc + (size_t)(h0 + r) * 2048 + cs;
        wA[r] = *(const float4*)(wr);
        wB[r] = *(const float4*)(wr + 4);
    }
#pragma unroll 2
    for (int n = 0; n < 16; ++n) {
        const float* cr = cat + (size_t)(nb + n) * 2048 + cs;
        const float4 xA = *(const float4*)(cr);
        const float4 xB = *(const float4*)(cr + 4);
        float d0, d1, d2, d3;
        d0 = xA.x * wA[0].x; d0 = fmaf(xA.y, wA[0].y, d0); d0 = fmaf(xA.z, wA[0].z, d0); d0 = fmaf(xA.w, wA[0].w, d0);
        d0 = fmaf(xB.x, wB[0].x, d0); d0 = fmaf(xB.y, wB[0].y, d0); d0 = fmaf(xB.z, wB[0].z, d0); d0 = fmaf(xB.w, wB[0].w, d0);
        d1 = xA.x * wA[1].x; d1 = fmaf(xA.y, wA[1].y, d1); d1 = fmaf(xA.z, wA[1].z, d1); d1 = fmaf(xA.w, wA[1].w, d1);
        d1 = fmaf(xB.x, wB[1].x, d1); d1 = fmaf(xB.y, wB[1].y, d1); d1 = fmaf(xB.z, wB[1].z, d1); d1 = fmaf(xB.w, wB[1].w, d1);
        d2 = xA.x * wA[2].x; d2 = fmaf(xA.y, wA[2].y, d2); d2 = fmaf(xA.z, wA[2].z, d2); d2 = fmaf(xA.w, wA[2].w, d2);
        d2 = fmaf(xB.x, wB[2].x, d2); d2 = fmaf(xB.y, wB[2].y, d2); d2 = fmaf(xB.z, wB[2].z, d2); d2 = fmaf(xB.w, wB[2].w, d2);
        d3 = xA.x * wA[3].x; d3 = fmaf(xA.y, wA[3].y, d3); d3 = fmaf(xA.z, wA[3].z, d3); d3 = fmaf(xA.w, wA[3].w, d3);
        d3 = fmaf(xB.x, wB[3].x, d3); d3 = fmaf(xB.y, wB[3].y, d3); d3 = fmaf(xB.z, wB[3].z, d3); d3 = fmaf(xB.w, wB[3].w, d3);
#pragma unroll
        for (int msk = 1; msk < 64; msk <<= 1) {
            d0 += __shfl_xor(d0, msk, 64);
            d1 += __shfl_xor(d1, msk, 64);
            d2 += __shfl_xor(d2, msk, 64);
            d3 += __shfl_xor(d3, msk, 64);
        }
        if (j == 0) *(float4*)&qbuf[q][n][0] = make_float4(d0, d1, d2, d3);
    }
    __syncthreads();
    // 64 threads: one (n, r) each; sum 4 quarters, tanh, store.
    if (tid < 64) {
        const int n = tid >> 2, r = tid & 3;
        const float s = qbuf[0][n][r] + qbuf[1][n][r] + qbuf[2][n][r] + qbuf[3][n][r];
        out[(size_t)(nb + n) * H_ + h0 + r] = tanhf(s);
    }
}

extern "C" void kernel_launch(void* const* d_in, const int* in_sizes, int n_in,
                              void* d_out, int out_size, void* d_ws, size_t ws_size,
                              hipStream_t stream) {
    const float* enc  = (const float*)d_in[0];
    const float* outp = (const float*)d_in[1];
    // d_in[2] = time_step (unused by the reference math)
    const float* Wa   = (const float*)d_in[3];
    const float* Wp   = (const float*)d_in[4];
    const float* vp   = (const float*)d_in[5];
    const float* Wc   = (const float*)d_in[6];
    float* ws  = (float*)d_ws;
    float* out = (float*)d_out;

    hipLaunchKernelGGL(k1_prep,   dim3(1024), dim3(256), 0, stream, outp, Wa, Wp, ws);
    hipLaunchKernelGGL(k1b_final, dim3(128),  dim3(256), 0, stream, vp, ws);
    hipLaunchKernelGGL(k2_stream, dim3(1024), dim3(256), 0, stream, enc, ws);
    hipLaunchKernelGGL(k3_combine,dim3(256),  dim3(256), 0, stream, outp, ws);
    hipLaunchKernelGGL(k4_fused,  dim3(1024), dim3(256), 0, stream, Wc, ws, out);
}